// Round 1
// 144.390 us; speedup vs baseline: 1.0218x; 1.0218x over previous
//
#include <hip/hip_runtime.h>
#include <hip/hip_bf16.h>
#include <stdint.h>

#define BATCH 4
#define SEQ   4096
#define EMB   1024
#define HD    64

typedef __bf16 bf16x8 __attribute__((ext_vector_type(8)));
typedef float  f32x4  __attribute__((ext_vector_type(4)));
typedef unsigned short u16;

// softmax in base-2 domain: logits pre-scaled by log2(e)/sqrt(EMB)
#define QSCALE 0.04508422002777948f

__device__ __forceinline__ u16 f2bf(float f) {
    union { __bf16 h; u16 u; } c; c.h = (__bf16)f; return c.u;
}
__device__ __forceinline__ float bf2f(u16 h) {
    union { uint32_t u; float f; } cv; cv.u = ((uint32_t)h) << 16;
    return cv.f;
}
__device__ __forceinline__ void gld16(const void* g, void* l) {
    __builtin_amdgcn_global_load_lds(
        (const __attribute__((address_space(1))) void*)g,
        (__attribute__((address_space(3))) void*)l, 16, 0, 0);
}

// ---------------------------------------------------------------------------
// Kernel 0: W (1024,64) fp32 x3 -> Wt bf16 [3][64][1024]  (transposed)
// ---------------------------------------------------------------------------
__global__ __launch_bounds__(256) void wt_kernel(
        const float* __restrict__ Wq, const float* __restrict__ Wk,
        const float* __restrict__ Wv, u16* __restrict__ Wt) {
    int idx = blockIdx.x * 256 + threadIdx.x;
    int i = idx >> 16;
    int r = idx & 65535;
    int n = r >> 10;
    int k = r & 1023;
    const float* W = (i == 0) ? Wq : (i == 1) ? Wk : Wv;
    Wt[idx] = f2bf(W[k * HD + n]);
}

// ---------------------------------------------------------------------------
// Kernel 1: QKV projection. 512 blocks, M=32 rows/block (2 blocks/CU).
// bf16 conversion now via native casts -> v_cvt_pk_bf16_f32 (1 op / 2 elems).
// Q written pre-scaled by log2(e)/32 so attention softmax runs in base 2.
// ---------------------------------------------------------------------------
__global__ __launch_bounds__(256) void qkv_kernel(
        const float* __restrict__ x, const u16* __restrict__ Wt,
        u16* __restrict__ Qw, u16* __restrict__ Kw, u16* __restrict__ Vt) {
    __shared__ float xs[2][2048];     // 2 x 8 KB : 32 rows x 16 chunks(16B)
    __shared__ u16   wsb[2][12288];   // 2 x 24 KB: 192 rows x 8 chunks(16B)

    const int t    = threadIdx.x;
    const int wave = t >> 6;
    const int lane = t & 63;
    const int m16  = lane & 15;
    const int quad = lane >> 4;
    const int rh   = wave & 1;
    const int ch   = wave >> 1;
    const int R0   = blockIdx.x * 32;

    #define ISSUE(buf_, kt_) do {                                              \
        const int r4_ = lane >> 4, c16_ = lane & 15;                           \
        _Pragma("unroll")                                                      \
        for (int j_ = 0; j_ < 2; ++j_) {                                       \
            const int ii_  = wave + (j_ << 2);                                 \
            const int row_ = (ii_ << 2) + r4_;            /* 0..31 */          \
            const int kc_  = c16_ ^ (row_ & 15);                               \
            gld16(x + (size_t)(R0 + row_) * EMB + ((kt_) << 6) + (kc_ << 2),   \
                  &xs[buf_][ii_ << 8]);                                        \
        }                                                                      \
        const int r8_ = lane >> 3, c8_ = lane & 7;                             \
        _Pragma("unroll")                                                      \
        for (int j_ = 0; j_ < 6; ++j_) {                                       \
            const int rb_ = (wave * 6 + j_) << 3;         /* 0..184 */         \
            const int kw_ = c8_ ^ r8_;                                         \
            gld16(Wt + (size_t)(rb_ + r8_) * 1024 + ((kt_) << 6) + (kw_ << 3), \
                  &wsb[buf_][(wave * 6 + j_) << 9]);                           \
        }                                                                      \
    } while (0)

    f32x4 acc[6];
#pragma unroll
    for (int a = 0; a < 6; ++a) acc[a] = (f32x4){0.f, 0.f, 0.f, 0.f};

    const int row_x = rh * 16 + m16;
    ISSUE(0, 0);

    for (int kt = 0; kt < 16; ++kt) {
        const int buf = kt & 1;
        __syncthreads();
        if (kt < 15) ISSUE(buf ^ 1, kt + 1);

#pragma unroll
        for (int ks2 = 0; ks2 < 2; ++ks2) {
            const int c0 = (ks2 << 3) + (quad << 1);
            const float4 a0 = *(const float4*)&xs[buf][(row_x << 6) + ((c0 ^ m16) << 2)];
            const float4 a1 = *(const float4*)&xs[buf][(row_x << 6) + (((c0 + 1) ^ m16) << 2)];
            union { bf16x8 v; __bf16 e[8]; } af;
            af.e[0] = (__bf16)a0.x; af.e[1] = (__bf16)a0.y;
            af.e[2] = (__bf16)a0.z; af.e[3] = (__bf16)a0.w;
            af.e[4] = (__bf16)a1.x; af.e[5] = (__bf16)a1.y;
            af.e[6] = (__bf16)a1.z; af.e[7] = (__bf16)a1.w;
#pragma unroll
            for (int i = 0; i < 6; ++i) {
                const int tt   = ch * 6 + i;
                const int rowW = (tt << 4) + m16;          // 0..191
                const bf16x8 bf = *(const bf16x8*)&wsb[buf][
                        (rowW << 6) + ((((ks2 << 2) + quad) ^ (m16 & 7)) << 3)];
                acc[i] = __builtin_amdgcn_mfma_f32_16x16x32_bf16(af.v, bf, acc[i], 0, 0, 0);
            }
        }
    }
    #undef ISSUE

    // C layout: lane holds rows quad*4+reg, col = tt*16 + m16 (global col 0..191)
    const int rowbase = R0 + rh * 16 + (quad << 2);
    const int bidx = rowbase >> 12;
    const int t0   = rowbase & 4095;
#pragma unroll
    for (int i = 0; i < 6; ++i) {
        const int tt  = ch * 6 + i;
        const int w3  = tt >> 2;
        const int col = ((tt & 3) << 4) + m16;
        if (w3 == 0) {
#pragma unroll
            for (int reg = 0; reg < 4; ++reg)
                Qw[(size_t)(rowbase + reg) * HD + col] = f2bf(acc[i][reg] * QSCALE);
        } else if (w3 == 1) {
#pragma unroll
            for (int reg = 0; reg < 4; ++reg)
                Kw[(size_t)(rowbase + reg) * HD + col] = f2bf(acc[i][reg]);
        } else {
            union { ushort4 vv; __bf16 e[4]; } o;
            o.e[0] = (__bf16)acc[i][0]; o.e[1] = (__bf16)acc[i][1];
            o.e[2] = (__bf16)acc[i][2]; o.e[3] = (__bf16)acc[i][3];
            *(ushort4*)(Vt + (size_t)((bidx << 6) + col) * SEQ + t0) = o.vv;
        }
    }
}

// ---------------------------------------------------------------------------
// Kernel 2: split-K causal flash attention, S^T formulation, LDS-staged K/V.
// Changes this round:
//  - P scratch: stride-64 + XOR chunk swizzle (chunk8 ^= m16&7) => LDS total
//    exactly 40960 B => 4 blocks/CU (was 41984 B pad => 3 blocks/CU + tail).
//  - base-2 softmax (Q pre-scaled by log2 e): bare v_exp_f32, no muls.
//  - deferred rescale (THR=8): skip alpha pass unless a row max moved >8.
//  - all fp32->bf16 via native casts (v_cvt_pk_bf16_f32).
// ---------------------------------------------------------------------------
__global__ __launch_bounds__(256, 4) void attn_part_kernel(
        const u16* __restrict__ Qw, const u16* __restrict__ Kw,
        const u16* __restrict__ Vt, u16* __restrict__ Opart,
        float* __restrict__ Mp, float* __restrict__ Lp) {
    __shared__ u16 kv[2][2][4096];     // [buf][K/V][64 rows x 8 chunks] = 32 KB
    __shared__ u16 ldsP[4][1024];      // per-wave P[q][k], 64 u16 row, swizzled

    const int pid = blockIdx.x;
    const int r   = pid >> 8;
    const int i   = pid & 255;
    const int b   = i & 3;
    const int h   = i >> 2;
    const int qt  = h ^ (int)((0x1f203f00u >> (r * 8)) & 63u);  // {0,63,32,31}[r]
    const int c   = r;
    const int p_out = (((b << 6) + qt) << 2) + c;

    const int wave = threadIdx.x >> 6;
    const int lane = threadIdx.x & 63;
    const int m16  = lane & 15;
    const int quad = lane >> 4;

    #define ISSUE_KV(buf_, jt_) do {                                           \
        const int r8_ = lane >> 3, c8_ = lane & 7;                             \
        const int kc_ = c8_ ^ r8_;                                             \
        _Pragma("unroll")                                                      \
        for (int j_ = 0; j_ < 2; ++j_) {                                       \
            const int row_ = ((wave * 2 + j_) << 3) + r8_;   /* 0..63 */       \
            gld16(Kw + ((size_t)(b * SEQ + ((jt_) << 6) + row_) << 6) + (kc_ << 3), \
                  &kv[buf_][0][(wave * 2 + j_) << 9]);                         \
            gld16(Vt + (size_t)((b << 6) + row_) * SEQ + ((jt_) << 6) + (kc_ << 3), \
                  &kv[buf_][1][(wave * 2 + j_) << 9]);                         \
        }                                                                      \
    } while (0)

    // Q fragment as B-operand: n = m16 = q-row, k = quad*8+j
    const int qrow = (qt << 6) + (wave << 4) + m16;
    const u16* qbase = Qw + ((size_t)(b * SEQ + qrow) << 6);
    const bf16x8 qf0 = *(const bf16x8*)(qbase + (quad << 3));
    const bf16x8 qf1 = *(const bf16x8*)(qbase + 32 + (quad << 3));

    f32x4 acc[4];     // O^T: lane q = m16, d = dt*16 + quad*4 + reg
#pragma unroll
    for (int dt = 0; dt < 4; ++dt) acc[dt] = (f32x4){0.f, 0.f, 0.f, 0.f};
    float m_i = -3.0e38f;
    float l_i = 0.f;

    u16* ldsW = &ldsP[wave][0];
    const int xs0 = (quad ^ (m16 & 7)) << 3;         // chunk slots for k-win 0
    const int xs1 = (((quad + 4)) ^ (m16 & 7)) << 3; // and k-win 1 (in u16)
    const int psw = m16 & 7;                          // P chunk swizzle key

    if (c <= qt) ISSUE_KV(0, c);

    int buf = 0;
    for (int jt = c; jt <= qt; jt += 4) {
        __syncthreads();                 // DMA of buf landed; buf^1 free
        if (jt + 4 <= qt) ISSUE_KV(buf ^ 1, jt + 4);

        // ---- S^T = K @ Q^T : A = K-frag from LDS ----
        f32x4 s[4];
#pragma unroll
        for (int mt = 0; mt < 4; ++mt) {
            const int base = ((mt << 4) + m16) << 6;
            bf16x8 k0 = *(const bf16x8*)&kv[buf][0][base + xs0];
            bf16x8 k1 = *(const bf16x8*)&kv[buf][0][base + xs1];
            s[mt] = (f32x4){0.f, 0.f, 0.f, 0.f};
            s[mt] = __builtin_amdgcn_mfma_f32_16x16x32_bf16(k0, qf0, s[mt], 0, 0, 0);
            s[mt] = __builtin_amdgcn_mfma_f32_16x16x32_bf16(k1, qf1, s[mt], 0, 0, 0);
        }

        if (jt == qt) {   // diagonal tile: mask k_in > q_in
            const int q_in = (wave << 4) + m16;
#pragma unroll
            for (int mt = 0; mt < 4; ++mt) {
                const int k_in = (mt << 4) + (quad << 2);
#pragma unroll
                for (int reg = 0; reg < 4; ++reg)
                    if (k_in + reg > q_in) s[mt][reg] = -3.0e38f;
            }
        }

        // ---- online softmax (base 2): lane owns one q-row ----
        float tm = fmaxf(fmaxf(s[0][0], s[0][1]), fmaxf(s[0][2], s[0][3]));
#pragma unroll
        for (int mt = 1; mt < 4; ++mt)
            tm = fmaxf(tm, fmaxf(fmaxf(s[mt][0], s[mt][1]), fmaxf(s[mt][2], s[mt][3])));
        tm = fmaxf(tm, __shfl_xor(tm, 16));
        tm = fmaxf(tm, __shfl_xor(tm, 32));

        // deferred rescale: only when some row max grows by > 8 (P <= 2^8)
        if (__any(tm > m_i + 8.0f)) {
            const float mnew  = fmaxf(m_i, tm);
            const float alpha = __builtin_amdgcn_exp2f(m_i - mnew);
            m_i = mnew;
            l_i *= alpha;
#pragma unroll
            for (int dt = 0; dt < 4; ++dt)
#pragma unroll
                for (int reg = 0; reg < 4; ++reg) acc[dt][reg] *= alpha;
        }

        float psum = 0.f;
#pragma unroll
        for (int mt = 0; mt < 4; ++mt) {
            const float p0 = __builtin_amdgcn_exp2f(s[mt][0] - m_i);
            const float p1 = __builtin_amdgcn_exp2f(s[mt][1] - m_i);
            const float p2 = __builtin_amdgcn_exp2f(s[mt][2] - m_i);
            const float p3 = __builtin_amdgcn_exp2f(s[mt][3] - m_i);
            psum += (p0 + p1) + (p2 + p3);
            union { ushort4 pv; __bf16 e[4]; } u;
            u.e[0] = (__bf16)p0; u.e[1] = (__bf16)p1;
            u.e[2] = (__bf16)p2; u.e[3] = (__bf16)p3;
            const int c8 = ((mt << 1) + (quad >> 1)) ^ psw;   // swizzled 16B chunk
            *(ushort4*)(ldsW + (m16 << 6) + (c8 << 3) + ((quad & 1) << 2)) = u.pv;
        }
        l_i += psum;

        // ---- O^T += V^T @ P^T : A = V-frag from LDS ----
        const bf16x8 p0 = *(const bf16x8*)(ldsW + (m16 << 6) + ((quad ^ psw) << 3));
        const bf16x8 p1 = *(const bf16x8*)(ldsW + (m16 << 6) + (((quad + 4) ^ psw) << 3));
#pragma unroll
        for (int dt = 0; dt < 4; ++dt) {
            const int base = ((dt << 4) + m16) << 6;
            bf16x8 v0 = *(const bf16x8*)&kv[buf][1][base + xs0];
            bf16x8 v1 = *(const bf16x8*)&kv[buf][1][base + xs1];
            acc[dt] = __builtin_amdgcn_mfma_f32_16x16x32_bf16(v0, p0, acc[dt], 0, 0, 0);
            acc[dt] = __builtin_amdgcn_mfma_f32_16x16x32_bf16(v1, p1, acc[dt], 0, 0, 0);
        }
        buf ^= 1;
    }
    #undef ISSUE_KV

    float l = l_i;
    l += __shfl_xor(l, 16);
    l += __shfl_xor(l, 32);

    u16* ob = Opart + (size_t)p_out * 4096;
    const int qin = (wave << 4) + m16;
#pragma unroll
    for (int dt = 0; dt < 4; ++dt) {
        union { ushort4 vv; __bf16 e[4]; } o;
        o.e[0] = (__bf16)acc[dt][0]; o.e[1] = (__bf16)acc[dt][1];
        o.e[2] = (__bf16)acc[dt][2]; o.e[3] = (__bf16)acc[dt][3];
        *(ushort4*)(ob + qin * 64 + (dt << 4) + (quad << 2)) = o.vv;
    }
    if (quad == 0) {
        Mp[p_out * 64 + qin] = m_i;
        Lp[p_out * 64 + qin] = l;
    }
}

// ---------------------------------------------------------------------------
// Kernel 3: combine the 4 chunk partials per (b, qtile, rowquarter), normalize.
// (m, l are in base-2 domain: use exp2.)
// ---------------------------------------------------------------------------
__global__ __launch_bounds__(256) void combine_kernel(
        const u16* __restrict__ Opart, const float* __restrict__ Mp,
        const float* __restrict__ Lp, float* __restrict__ out) {
    __shared__ float sm[4][16];
    __shared__ float sl[4][16];
    const int bq = blockIdx.x >> 2;          // b*64 + qt
    const int rq = blockIdx.x & 3;           // row quarter
    const int pidbase = bq << 2;
    const int t = threadIdx.x;
    if (t < 64) {
        const int cc = t >> 4, rr = t & 15;
        sm[cc][rr] = Mp[(pidbase + cc) * 64 + rq * 16 + rr];
        sl[cc][rr] = Lp[(pidbase + cc) * 64 + rq * 16 + rr];
    }
    __syncthreads();

    const int row_l = t >> 4;                // 0..15
    const int c4    = (t & 15) << 2;         // col base
    const int row   = rq * 16 + row_l;

    const float M = fmaxf(fmaxf(sm[0][row_l], sm[1][row_l]),
                          fmaxf(sm[2][row_l], sm[3][row_l]));
    float n0 = 0.f, n1 = 0.f, n2 = 0.f, n3 = 0.f, den = 0.f;
#pragma unroll
    for (int cc = 0; cc < 4; ++cc) {
        const float w = __builtin_amdgcn_exp2f(sm[cc][row_l] - M);
        den += w * sl[cc][row_l];
        const ushort4 op = *(const ushort4*)&Opart[
                (size_t)(pidbase + cc) * 4096 + row * 64 + c4];
        n0 += w * bf2f(op.x); n1 += w * bf2f(op.y);
        n2 += w * bf2f(op.z); n3 += w * bf2f(op.w);
    }
    const float rd = 1.0f / den;
    float4 o; o.x = n0 * rd; o.y = n1 * rd; o.z = n2 * rd; o.w = n3 * rd;
    *(float4*)&out[((size_t)bq << 12) + (row << 6) + c4] = o;
}

// ---------------------------------------------------------------------------
extern "C" void kernel_launch(void* const* d_in, const int* in_sizes, int n_in,
                              void* d_out, int out_size, void* d_ws, size_t ws_size,
                              hipStream_t stream) {
    const float* x  = (const float*)d_in[0];
    const float* Wq = (const float*)d_in[1];
    const float* Wk = (const float*)d_in[2];
    const float* Wv = (const float*)d_in[3];
    float* out = (float*)d_out;

    char* ws = (char*)d_ws;
    u16* Qw    = (u16*)(ws);                        // 2 MB
    u16* Kw    = (u16*)(ws + (2u << 20));           // 2 MB
    u16* Vt    = (u16*)(ws + (4u << 20));           // 2 MB  [b][64][T]
    u16* Wt    = (u16*)(ws + (6u << 20));           // 384 KB
    u16* Opart = (u16*)(ws + (13u << 19));          // 8 MB
    float* Mp  = (float*)(ws + (29u << 19));        // 256 KB
    float* Lp  = (float*)(ws + (59u << 18));        // 256 KB

    wt_kernel<<<768, 256, 0, stream>>>(Wq, Wk, Wv, Wt);
    qkv_kernel<<<512, 256, 0, stream>>>(x, Wt, Qw, Kw, Vt);
    attn_part_kernel<<<1024, 256, 0, stream>>>(Qw, Kw, Vt, Opart, Mp, Lp);
    combine_kernel<<<1024, 256, 0, stream>>>(Opart, Mp, Lp, out);
}

// Round 2
// 143.352 us; speedup vs baseline: 1.0291x; 1.0072x over previous
//
#include <hip/hip_runtime.h>
#include <hip/hip_bf16.h>
#include <stdint.h>

#define BATCH 4
#define SEQ   4096
#define EMB   1024
#define HD    64

typedef __bf16 bf16x8 __attribute__((ext_vector_type(8)));
typedef float  f32x4  __attribute__((ext_vector_type(4)));
typedef float  f32x16 __attribute__((ext_vector_type(16)));
typedef unsigned u32x2v __attribute__((ext_vector_type(2)));
typedef unsigned short u16;

// softmax in base-2 domain: logits pre-scaled by log2(e)/sqrt(EMB)
#define QSCALE 0.04508422002777948f

__device__ __forceinline__ u16 f2bf(float f) {
    union { __bf16 h; u16 u; } c; c.h = (__bf16)f; return c.u;
}
__device__ __forceinline__ unsigned pk2(float lo, float hi) {
    union { __bf16 e[2]; unsigned u; } c;
    c.e[0] = (__bf16)lo; c.e[1] = (__bf16)hi; return c.u;
}
__device__ __forceinline__ void gld16(const void* g, void* l) {
    __builtin_amdgcn_global_load_lds(
        (const __attribute__((address_space(1))) void*)g,
        (__attribute__((address_space(3))) void*)l, 16, 0, 0);
}
// exchange: a' = {A.lo self | B.lo from partner}, b' = {A.hi from partner | B.hi self}
__device__ __forceinline__ void halfswap(unsigned &a, unsigned &b) {
#if __has_builtin(__builtin_amdgcn_permlane32_swap)
    u32x2v r = __builtin_amdgcn_permlane32_swap(a, b, false, false);
    a = r.x; b = r.y;
#else
    const unsigned pa = (unsigned)__shfl_xor((int)a, 32);
    const unsigned pb = (unsigned)__shfl_xor((int)b, 32);
    const bool hi = (threadIdx.x & 32) != 0;
    const unsigned na = hi ? pb : a;
    const unsigned nb = hi ? b : pa;
    a = na; b = nb;
#endif
}

// ---------------------------------------------------------------------------
// Kernel 0: W (1024,64) fp32 x3 -> Wt bf16 [3][64][1024]  (transposed)
// ---------------------------------------------------------------------------
__global__ __launch_bounds__(256) void wt_kernel(
        const float* __restrict__ Wq, const float* __restrict__ Wk,
        const float* __restrict__ Wv, u16* __restrict__ Wt) {
    int idx = blockIdx.x * 256 + threadIdx.x;
    int i = idx >> 16;
    int r = idx & 65535;
    int n = r >> 10;
    int k = r & 1023;
    const float* W = (i == 0) ? Wq : (i == 1) ? Wk : Wv;
    Wt[idx] = f2bf(W[k * HD + n]);
}

// ---------------------------------------------------------------------------
// Kernel 1: QKV projection (unchanged from last round; passed).
// ---------------------------------------------------------------------------
__global__ __launch_bounds__(256) void qkv_kernel(
        const float* __restrict__ x, const u16* __restrict__ Wt,
        u16* __restrict__ Qw, u16* __restrict__ Kw, u16* __restrict__ Vt) {
    __shared__ float xs[2][2048];     // 2 x 8 KB : 32 rows x 16 chunks(16B)
    __shared__ u16   wsb[2][12288];   // 2 x 24 KB: 192 rows x 8 chunks(16B)

    const int t    = threadIdx.x;
    const int wave = t >> 6;
    const int lane = t & 63;
    const int m16  = lane & 15;
    const int quad = lane >> 4;
    const int rh   = wave & 1;
    const int ch   = wave >> 1;
    const int R0   = blockIdx.x * 32;

    #define ISSUE(buf_, kt_) do {                                              \
        const int r4_ = lane >> 4, c16_ = lane & 15;                           \
        _Pragma("unroll")                                                      \
        for (int j_ = 0; j_ < 2; ++j_) {                                       \
            const int ii_  = wave + (j_ << 2);                                 \
            const int row_ = (ii_ << 2) + r4_;            /* 0..31 */          \
            const int kc_  = c16_ ^ (row_ & 15);                               \
            gld16(x + (size_t)(R0 + row_) * EMB + ((kt_) << 6) + (kc_ << 2),   \
                  &xs[buf_][ii_ << 8]);                                        \
        }                                                                      \
        const int r8_ = lane >> 3, c8_ = lane & 7;                             \
        _Pragma("unroll")                                                      \
        for (int j_ = 0; j_ < 6; ++j_) {                                       \
            const int rb_ = (wave * 6 + j_) << 3;         /* 0..184 */         \
            const int kw_ = c8_ ^ r8_;                                         \
            gld16(Wt + (size_t)(rb_ + r8_) * 1024 + ((kt_) << 6) + (kw_ << 3), \
                  &wsb[buf_][(wave * 6 + j_) << 9]);                           \
        }                                                                      \
    } while (0)

    f32x4 acc[6];
#pragma unroll
    for (int a = 0; a < 6; ++a) acc[a] = (f32x4){0.f, 0.f, 0.f, 0.f};

    const int row_x = rh * 16 + m16;
    ISSUE(0, 0);

    for (int kt = 0; kt < 16; ++kt) {
        const int buf = kt & 1;
        __syncthreads();
        if (kt < 15) ISSUE(buf ^ 1, kt + 1);

#pragma unroll
        for (int ks2 = 0; ks2 < 2; ++ks2) {
            const int c0 = (ks2 << 3) + (quad << 1);
            const float4 a0 = *(const float4*)&xs[buf][(row_x << 6) + ((c0 ^ m16) << 2)];
            const float4 a1 = *(const float4*)&xs[buf][(row_x << 6) + (((c0 + 1) ^ m16) << 2)];
            union { bf16x8 v; __bf16 e[8]; } af;
            af.e[0] = (__bf16)a0.x; af.e[1] = (__bf16)a0.y;
            af.e[2] = (__bf16)a0.z; af.e[3] = (__bf16)a0.w;
            af.e[4] = (__bf16)a1.x; af.e[5] = (__bf16)a1.y;
            af.e[6] = (__bf16)a1.z; af.e[7] = (__bf16)a1.w;
#pragma unroll
            for (int i = 0; i < 6; ++i) {
                const int tt   = ch * 6 + i;
                const int rowW = (tt << 4) + m16;          // 0..191
                const bf16x8 bf = *(const bf16x8*)&wsb[buf][
                        (rowW << 6) + ((((ks2 << 2) + quad) ^ (m16 & 7)) << 3)];
                acc[i] = __builtin_amdgcn_mfma_f32_16x16x32_bf16(af.v, bf, acc[i], 0, 0, 0);
            }
        }
    }
    #undef ISSUE

    const int rowbase = R0 + rh * 16 + (quad << 2);
    const int bidx = rowbase >> 12;
    const int t0   = rowbase & 4095;
#pragma unroll
    for (int i = 0; i < 6; ++i) {
        const int tt  = ch * 6 + i;
        const int w3  = tt >> 2;
        const int col = ((tt & 3) << 4) + m16;
        if (w3 == 0) {
#pragma unroll
            for (int reg = 0; reg < 4; ++reg)
                Qw[(size_t)(rowbase + reg) * HD + col] = f2bf(acc[i][reg] * QSCALE);
        } else if (w3 == 1) {
#pragma unroll
            for (int reg = 0; reg < 4; ++reg)
                Kw[(size_t)(rowbase + reg) * HD + col] = f2bf(acc[i][reg]);
        } else {
            union { ushort4 vv; __bf16 e[4]; } o;
            o.e[0] = (__bf16)acc[i][0]; o.e[1] = (__bf16)acc[i][1];
            o.e[2] = (__bf16)acc[i][2]; o.e[3] = (__bf16)acc[i][3];
            *(ushort4*)(Vt + (size_t)((bidx << 6) + col) * SEQ + t0) = o.vv;
        }
    }
}

// ---------------------------------------------------------------------------
// Kernel 2: split-K causal flash attention, 32x32x16 MFMA, QBLK=128, KVBLK=64.
// 4 waves; wave w owns q-cols qt*128 + w*32 + (lane&31) for the FULL k-tile.
// S^T C-layout: col=q=lane&31, k-row=(reg&3)+8*(reg>>2)+4*(lane>>5).
// Lane pair (l, l+32) shares q -> softmax = in-lane max over 32 + 1 shfl.
// P never touches LDS: cvt_pk pairs + permlane32_swap build the PV B-frags.
// 8 split-K chunks, grid 1024, LDS 32 KB -> 4 blocks/CU.
// ---------------------------------------------------------------------------
__global__ __launch_bounds__(256, 4) void attn_part_kernel(
        const u16* __restrict__ Qw, const u16* __restrict__ Kw,
        const u16* __restrict__ Vt, float* __restrict__ Opart,
        float* __restrict__ Mp, float* __restrict__ Lp) {
    __shared__ u16 kv[2][2][4096];   // [buf][K/V][64 rows x 8 chunks(16B)] = 32 KB

    const int pid = blockIdx.x;
    const int c   = pid >> 7;                 // chunk 0..7
    const int i   = pid & 127;
    const int b   = i & 3;
    const int hq  = i >> 2;                   // 0..31
    const int qt  = hq ^ (int)((0x071817080F101F00ULL >> (c * 8)) & 31u);
    const int part = (((b << 5) + qt) << 3) + c;
    const int jmax = 2 * qt + 1;

    const int wave = threadIdx.x >> 6;
    const int lane = threadIdx.x & 63;
    const int l31  = lane & 31;
    const int h    = lane >> 5;

    #define ISSUE_KV(buf_, jt_) do {                                           \
        const int r8_ = lane >> 3, c8_ = lane & 7;                             \
        const int kc_ = c8_ ^ r8_;                                             \
        _Pragma("unroll")                                                      \
        for (int j_ = 0; j_ < 2; ++j_) {                                       \
            const int row_ = ((wave * 2 + j_) << 3) + r8_;   /* 0..63 */       \
            gld16(Kw + ((size_t)(b * SEQ + ((jt_) << 6) + row_) << 6) + (kc_ << 3), \
                  &kv[buf_][0][(wave * 2 + j_) << 9]);                         \
            gld16(Vt + (size_t)((b << 6) + row_) * SEQ + ((jt_) << 6) + (kc_ << 3), \
                  &kv[buf_][1][(wave * 2 + j_) << 9]);                         \
        }                                                                      \
    } while (0)

    // Q fragments as B-operand: col = l31 (q), k = s*16 + h*8 + e
    const int qg = (qt << 7) + (wave << 5) + l31;
    const u16* qbase = Qw + ((size_t)(b * SEQ + qg) << 6);
    bf16x8 qf[4];
#pragma unroll
    for (int s = 0; s < 4; ++s)
        qf[s] = *(const bf16x8*)(qbase + (s << 4) + (h << 3));

    f32x16 o[2];
#pragma unroll
    for (int dt = 0; dt < 2; ++dt)
#pragma unroll
        for (int k = 0; k < 16; ++k) o[dt][k] = 0.f;
    float m_i = -3.0e38f, l_i = 0.f;
    const int qmin_w = (qt << 7) + (wave << 5);

    if (c <= jmax) ISSUE_KV(0, c);

    int buf = 0;
    for (int jt = c; jt <= jmax; jt += 8) {
        __syncthreads();                  // DMA of buf landed; buf^1 free
        if (jt + 8 <= jmax) ISSUE_KV(buf ^ 1, jt + 8);

        if ((jt << 6) <= qmin_w + 31) {   // quadrant not fully masked
            // ---- S^T = K @ Q^T, 2 tiles of 32 k-rows ----
            f32x16 s2[2];
#pragma unroll
            for (int mt = 0; mt < 2; ++mt) {
                f32x16 sa;
#pragma unroll
                for (int k = 0; k < 16; ++k) sa[k] = 0.f;
                const int row = (mt << 5) + l31;
                const int rb  = row << 6;
                const int rx  = row & 7;
#pragma unroll
                for (int s = 0; s < 4; ++s) {
                    const bf16x8 kf = *(const bf16x8*)&kv[buf][0][
                            rb + ((((s << 1) + h) ^ rx) << 3)];
                    sa = __builtin_amdgcn_mfma_f32_32x32x16_bf16(kf, qf[s], sa, 0, 0, 0);
                }
                s2[mt] = sa;
            }

            // ---- causal mask (diagonal band only) ----
            if ((jt << 6) + 63 > qmin_w) {
#pragma unroll
                for (int mt = 0; mt < 2; ++mt)
#pragma unroll
                for (int reg = 0; reg < 16; ++reg) {
                    const int kg = (jt << 6) + (mt << 5) +
                                   (reg & 3) + ((reg >> 2) << 3) + (h << 2);
                    if (kg > qg) s2[mt][reg] = -3.0e38f;
                }
            }

            // ---- online softmax (base 2), lane pair (l, l^32) shares q ----
            float tm = s2[0][0];
#pragma unroll
            for (int mt = 0; mt < 2; ++mt)
#pragma unroll
            for (int reg = 0; reg < 16; ++reg) tm = fmaxf(tm, s2[mt][reg]);
            tm = fmaxf(tm, __shfl_xor(tm, 32));

            if (__any(tm > m_i + 8.0f)) {      // deferred rescale, THR=8
                const float mnew = fmaxf(m_i, tm);
                const float al = __builtin_amdgcn_exp2f(m_i - mnew);
                m_i = mnew; l_i *= al;
#pragma unroll
                for (int dt = 0; dt < 2; ++dt)
#pragma unroll
                for (int k = 0; k < 16; ++k) o[dt][k] *= al;
            }

            float ps = 0.f;
#pragma unroll
            for (int mt = 0; mt < 2; ++mt)
#pragma unroll
            for (int reg = 0; reg < 16; ++reg) {
                const float p = __builtin_amdgcn_exp2f(s2[mt][reg] - m_i);
                s2[mt][reg] = p; ps += p;
            }
            l_i += ps;

            // ---- P -> PV B-frags in registers (cvt_pk + permlane32_swap) ----
            union F { unsigned d[4]; bf16x8 v; } pf[4];
#pragma unroll
            for (int mt = 0; mt < 2; ++mt) {
                unsigned A0 = pk2(s2[mt][0],  s2[mt][1]);
                unsigned B0 = pk2(s2[mt][4],  s2[mt][5]);
                unsigned C0 = pk2(s2[mt][2],  s2[mt][3]);
                unsigned D0 = pk2(s2[mt][6],  s2[mt][7]);
                halfswap(A0, B0); halfswap(C0, D0);
                pf[2*mt].d[0] = A0; pf[2*mt].d[1] = C0;
                pf[2*mt].d[2] = B0; pf[2*mt].d[3] = D0;
                unsigned A1 = pk2(s2[mt][8],  s2[mt][9]);
                unsigned B1 = pk2(s2[mt][12], s2[mt][13]);
                unsigned C1 = pk2(s2[mt][10], s2[mt][11]);
                unsigned D1 = pk2(s2[mt][14], s2[mt][15]);
                halfswap(A1, B1); halfswap(C1, D1);
                pf[2*mt+1].d[0] = A1; pf[2*mt+1].d[1] = C1;
                pf[2*mt+1].d[2] = B1; pf[2*mt+1].d[3] = D1;
            }

            // ---- O^T += V^T @ P^T ----
#pragma unroll
            for (int dt = 0; dt < 2; ++dt) {
                const int row = (dt << 5) + l31;
                const int rb  = row << 6;
                const int rx  = row & 7;
                f32x16 oa = o[dt];
#pragma unroll
                for (int s = 0; s < 4; ++s) {
                    const bf16x8 vf = *(const bf16x8*)&kv[buf][1][
                            rb + ((((s << 1) + h) ^ rx) << 3)];
                    oa = __builtin_amdgcn_mfma_f32_32x32x16_bf16(vf, pf[s].v, oa, 0, 0, 0);
                }
                o[dt] = oa;
            }
        }
        buf ^= 1;
    }
    #undef ISSUE_KV

    const float l2 = l_i + __shfl_xor(l_i, 32);

    // Opart fp32 [part][d=64][q=128], coalesced dword stores
    float* ob = Opart + ((size_t)part << 13) + (wave << 5) + l31;
#pragma unroll
    for (int dt = 0; dt < 2; ++dt)
#pragma unroll
    for (int reg = 0; reg < 16; ++reg) {
        const int d = (dt << 5) + (reg & 3) + ((reg >> 2) << 3) + (h << 2);
        ob[d << 7] = o[dt][reg];
    }
    if (lane < 32) {
        Mp[part * 128 + (wave << 5) + l31] = m_i;
        Lp[part * 128 + (wave << 5) + l31] = l2;
    }
}

// ---------------------------------------------------------------------------
// Kernel 3: combine 8 chunk partials per (b,qt), normalize. Grid 256.
// Thread owns (q, 16 d): reads coalesced along q, writes one full 64B line.
// ---------------------------------------------------------------------------
__global__ __launch_bounds__(256) void combine_kernel(
        const float* __restrict__ Opart, const float* __restrict__ Mp,
        const float* __restrict__ Lp, float* __restrict__ out) {
    const int gb = blockIdx.x;
    const int bq = gb >> 1;                  // b*32 + qt
    const int qh = gb & 1;
    const int t  = threadIdx.x;
    const int ql = (qh << 6) + (t & 63);     // 0..127
    const int d0 = (t >> 6) << 4;            // 0,16,32,48
    const int pb = bq << 3;

    float mv[8];
    float M = -3.0e38f;
#pragma unroll
    for (int cc = 0; cc < 8; ++cc) {
        mv[cc] = Mp[(pb + cc) * 128 + ql];
        M = fmaxf(M, mv[cc]);
    }
    float o16[16];
#pragma unroll
    for (int k = 0; k < 16; ++k) o16[k] = 0.f;
    float den = 0.f;
#pragma unroll
    for (int cc = 0; cc < 8; ++cc) {
        const float w = __builtin_amdgcn_exp2f(mv[cc] - M);
        den += w * Lp[(pb + cc) * 128 + ql];
        const float* op = Opart + ((size_t)(pb + cc) << 13) + ql;
#pragma unroll
        for (int k = 0; k < 16; ++k)
            o16[k] = fmaf(w, op[(d0 + k) << 7], o16[k]);
    }
    const float rd = 1.0f / den;
    float* orow = out + (((size_t)bq << 7) + ql) * 64 + d0;
#pragma unroll
    for (int j = 0; j < 4; ++j) {
        float4 v;
        v.x = o16[4*j]     * rd; v.y = o16[4*j + 1] * rd;
        v.z = o16[4*j + 2] * rd; v.w = o16[4*j + 3] * rd;
        *(float4*)(orow + 4*j) = v;
    }
}

// ---------------------------------------------------------------------------
extern "C" void kernel_launch(void* const* d_in, const int* in_sizes, int n_in,
                              void* d_out, int out_size, void* d_ws, size_t ws_size,
                              hipStream_t stream) {
    const float* x  = (const float*)d_in[0];
    const float* Wq = (const float*)d_in[1];
    const float* Wk = (const float*)d_in[2];
    const float* Wv = (const float*)d_in[3];
    float* out = (float*)d_out;

    char* ws = (char*)d_ws;
    u16* Qw     = (u16*)(ws);                          // 2 MB
    u16* Kw     = (u16*)(ws + (2u << 20));             // 2 MB
    u16* Vt     = (u16*)(ws + (4u << 20));             // 2 MB  [b][64][T]
    u16* Wt     = (u16*)(ws + (6u << 20));             // 384 KB
    float* Opart = (float*)(ws + (8u << 20));          // 32 MB [1024][64][128]
    float* Mp   = (float*)(ws + (40u << 20));          // 512 KB
    float* Lp   = (float*)(ws + (40u << 20) + (512u << 10)); // 512 KB

    wt_kernel<<<768, 256, 0, stream>>>(Wq, Wk, Wv, Wt);
    qkv_kernel<<<512, 256, 0, stream>>>(x, Wt, Qw, Kw, Vt);
    attn_part_kernel<<<1024, 256, 0, stream>>>(Qw, Kw, Vt, Opart, Mp, Lp);
    combine_kernel<<<256, 256, 0, stream>>>(Opart, Mp, Lp, out);
}